// Round 1
// baseline (23.414 us; speedup 1.0000x reference)
//
#include <hip/hip_runtime.h>

// votes[b,n,m,o] = sum_i inputs[b,n,i] * W[n,m,i,o]
// B=64, N_IN=1152, N_OUT=10, D_IN=8, D_OUT=16
// Memory-bound: 47 MB output write dominates. One thread per float4 of output.

constexpr int B     = 64;
constexpr int N_IN  = 1152;
constexpr int N_OUT = 10;
constexpr int D_IN  = 8;
constexpr int D_OUT = 16;
constexpr int TOTAL4 = B * N_IN * N_OUT * (D_OUT / 4);  // 2,949,120 float4s

__global__ __launch_bounds__(256)
void Transforming_56195352101061_kernel(const float* __restrict__ in,
                                        const float* __restrict__ W,
                                        float* __restrict__ out) {
    int tid = blockIdx.x * blockDim.x + threadIdx.x;
    if (tid >= TOTAL4) return;

    int o4  = tid & 3;        // which float4 within D_OUT (D_OUT/4 = 4)
    int rem = tid >> 2;       // (b, n, m) linear
    int m   = rem % N_OUT;
    rem    /= N_OUT;
    int n   = rem % N_IN;
    int b   = rem / N_IN;

    // inputs[b,n,0..7] — two float4 loads (32B aligned), broadcast across lanes
    const float4* inv = reinterpret_cast<const float4*>(
        in + (size_t)(b * N_IN + n) * D_IN);
    float4 i0 = inv[0];
    float4 i1 = inv[1];
    float ivals[8] = {i0.x, i0.y, i0.z, i0.w, i1.x, i1.y, i1.z, i1.w};

    // W[n,m,i,o] — float4 per i, coalesced in o across lanes
    const float* wbase = W + ((size_t)(n * N_OUT + m) * D_IN) * D_OUT + o4 * 4;

    float4 acc = {0.f, 0.f, 0.f, 0.f};
#pragma unroll
    for (int i = 0; i < D_IN; ++i) {
        float4 w = *reinterpret_cast<const float4*>(wbase + i * D_OUT);
        acc.x += ivals[i] * w.x;
        acc.y += ivals[i] * w.y;
        acc.z += ivals[i] * w.z;
        acc.w += ivals[i] * w.w;
    }

    reinterpret_cast<float4*>(out)[tid] = acc;
}

extern "C" void kernel_launch(void* const* d_in, const int* in_sizes, int n_in,
                              void* d_out, int out_size, void* d_ws, size_t ws_size,
                              hipStream_t stream) {
    const float* in = (const float*)d_in[0];   // [B, N_IN, 8, 1]
    const float* W  = (const float*)d_in[1];   // [1, N_IN, N_OUT, 8, 16, 1]
    float* out      = (float*)d_out;           // [B, N_IN, N_OUT, 16, 1]

    constexpr int BLOCK = 256;
    constexpr int GRID  = (TOTAL4 + BLOCK - 1) / BLOCK;  // 11520
    Transforming_56195352101061_kernel<<<GRID, BLOCK, 0, stream>>>(in, W, out);
}

// Round 2
// 15.679 us; speedup vs baseline: 1.4933x; 1.4933x over previous
//
#include <hip/hip_runtime.h>

// votes[b,n,m,o] = sum_i inputs[b,n,i] * W[n,m,i,o]
// B=64, N_IN=1152, N_OUT=10, D_IN=8, D_OUT=16
// Round 1 insight: W-read amplification (377 MB of L2/L3 traffic) was the
// bottleneck, not HBM. Amortize each W load across KB=8 batch elements.

constexpr int B     = 64;
constexpr int N_IN  = 1152;
constexpr int N_OUT = 10;
constexpr int D_IN  = 8;
constexpr int D_OUT = 16;
constexpr int KB    = 8;                                   // b values per thread
constexpr int NTHREADS = N_IN * N_OUT * (D_OUT / 4) * (B / KB);  // 368,640

__global__ __launch_bounds__(256)
void Transforming_56195352101061_kernel(const float* __restrict__ in,
                                        const float* __restrict__ W,
                                        float* __restrict__ out) {
    int tid = blockIdx.x * blockDim.x + threadIdx.x;
    if (tid >= NTHREADS) return;

    // tid = ((bb*N_IN + n)*N_OUT + m)*4 + o4  -> consecutive tids coalesce
    // in (n,m,o4) at fixed b-block for both W reads and output writes.
    int lin = tid;
    int o4 = lin & 3;       lin >>= 2;
    int m  = lin % N_OUT;   lin /= N_OUT;
    int n  = lin % N_IN;
    int bb = lin / N_IN;    // which block of KB batch elements

    // Load this thread's W column once: 8 float4s (one per i).
    const float* wbase = W + ((size_t)(n * N_OUT + m) * D_IN) * D_OUT + o4 * 4;
    float4 w[D_IN];
#pragma unroll
    for (int i = 0; i < D_IN; ++i)
        w[i] = *reinterpret_cast<const float4*>(wbase + i * D_OUT);

    const float* ibase = in + ((size_t)(bb * KB) * N_IN + n) * D_IN;
    float4* out4 = reinterpret_cast<float4*>(out);

#pragma unroll
    for (int j = 0; j < KB; ++j) {
        int b = bb * KB + j;
        const float4* iv = reinterpret_cast<const float4*>(
            ibase + (size_t)j * N_IN * D_IN);
        float4 i0 = iv[0];
        float4 i1 = iv[1];
        float ivals[8] = {i0.x, i0.y, i0.z, i0.w, i1.x, i1.y, i1.z, i1.w};

        float4 acc = {0.f, 0.f, 0.f, 0.f};
#pragma unroll
        for (int i = 0; i < D_IN; ++i) {
            acc.x += ivals[i] * w[i].x;
            acc.y += ivals[i] * w[i].y;
            acc.z += ivals[i] * w[i].z;
            acc.w += ivals[i] * w[i].w;
        }

        out4[((size_t)(b * N_IN + n) * N_OUT + m) * 4 + o4] = acc;
    }
}

extern "C" void kernel_launch(void* const* d_in, const int* in_sizes, int n_in,
                              void* d_out, int out_size, void* d_ws, size_t ws_size,
                              hipStream_t stream) {
    const float* in = (const float*)d_in[0];   // [B, N_IN, 8, 1]
    const float* W  = (const float*)d_in[1];   // [1, N_IN, N_OUT, 8, 16, 1]
    float* out      = (float*)d_out;           // [B, N_IN, N_OUT, 16, 1]

    constexpr int BLOCK = 256;
    constexpr int GRID  = (NTHREADS + BLOCK - 1) / BLOCK;  // 1440
    Transforming_56195352101061_kernel<<<GRID, BLOCK, 0, stream>>>(in, W, out);
}

// Round 4
// 14.125 us; speedup vs baseline: 1.6577x; 1.1100x over previous
//
#include <hip/hip_runtime.h>

// votes[b,n,m,o] = sum_i inputs[b,n,i] * W[n,m,i,o]
// B=64, N_IN=1152, N_OUT=10, D_IN=8, D_OUT=16
// Round 2 insight: combined traffic (47MB write + 47MB W-read) ran at the
// 6.4 TB/s fabric ceiling. Fix: XCD-swizzle so all 8 batch-replicas of a
// (n,m,o4) chunk share one XCD's L2 (W footprint/XCD: 5.9MB -> 0.74MB),
// plus non-temporal stores so the write stream doesn't evict W from L2.
// Round 3: __builtin_nontemporal_store needs a native vector type, not
// HIP_vector_type — use ext_vector_type(4).

typedef float floatx4 __attribute__((ext_vector_type(4)));

constexpr int B     = 64;
constexpr int N_IN  = 1152;
constexpr int N_OUT = 10;
constexpr int D_IN  = 8;
constexpr int D_OUT = 16;
constexpr int KB    = 8;                       // b values per thread
constexpr int NCHUNK = N_IN * N_OUT * 4 / 256; // 180 chunks of 256 threads
constexpr int NBLOCKS = NCHUNK * (B / KB);     // 1440

__global__ __launch_bounds__(256)
void Transforming_56195352101061_kernel(const float* __restrict__ in,
                                        const float* __restrict__ W,
                                        float* __restrict__ out) {
    // Swizzle: blockIdx.x -> (bb, c) such that blockIdx.x % 8 is a function
    // of c only (for the first 1408 blocks). All 8 bb-replicas of chunk c
    // then land on the same XCD (assuming xcd = dispatch_order % 8).
    int id = blockIdx.x;
    int bb, c;
    if (id < 1408) {                 // 8 r * 8 bb * 22 g
        int r = id & 7;
        int t = id >> 3;
        bb    = t & 7;
        c     = (t >> 3) * 8 + r;    // c = 8g + r, g in [0,22)
    } else {                         // tail: c in [176,180), 2% of blocks
        int k = id - 1408;
        bb    = k >> 2;
        c     = 176 + (k & 3);
    }

    int tid = c * 256 + (int)threadIdx.x;   // [0, 46080) over (n,m,o4)
    int o4  = tid & 3;
    int lin = tid >> 2;
    int m   = lin % N_OUT;
    int n   = lin / N_OUT;

    // Load this thread's W column once: 8 float4s (one per i). L2-resident.
    const float* wbase = W + ((size_t)(n * N_OUT + m) * D_IN) * D_OUT + o4 * 4;
    floatx4 w[D_IN];
#pragma unroll
    for (int i = 0; i < D_IN; ++i)
        w[i] = *reinterpret_cast<const floatx4*>(wbase + i * D_OUT);

    const float* ibase = in + ((size_t)(bb * KB) * N_IN + n) * D_IN;
    floatx4* out4 = reinterpret_cast<floatx4*>(out);

#pragma unroll
    for (int j = 0; j < KB; ++j) {
        int b = bb * KB + j;
        const floatx4* iv = reinterpret_cast<const floatx4*>(
            ibase + (size_t)j * N_IN * D_IN);
        floatx4 i0 = iv[0];
        floatx4 i1 = iv[1];
        float ivals[8] = {i0.x, i0.y, i0.z, i0.w, i1.x, i1.y, i1.z, i1.w};

        floatx4 acc = {0.f, 0.f, 0.f, 0.f};
#pragma unroll
        for (int i = 0; i < D_IN; ++i) {
            acc += ivals[i] * w[i];
        }

        // Streaming store: don't pollute L2 (keeps W resident).
        __builtin_nontemporal_store(acc,
            &out4[((size_t)(b * N_IN + n) * N_OUT + m) * 4 + o4]);
    }
}

extern "C" void kernel_launch(void* const* d_in, const int* in_sizes, int n_in,
                              void* d_out, int out_size, void* d_ws, size_t ws_size,
                              hipStream_t stream) {
    const float* in = (const float*)d_in[0];   // [B, N_IN, 8, 1]
    const float* W  = (const float*)d_in[1];   // [1, N_IN, N_OUT, 8, 16, 1]
    float* out      = (float*)d_out;           // [B, N_IN, N_OUT, 16, 1]

    Transforming_56195352101061_kernel<<<NBLOCKS, 256, 0, stream>>>(in, W, out);
}